// Round 5
// baseline (104.127 us; speedup 1.0000x reference)
//
#include <hip/hip_runtime.h>
#include <math.h>

#define NPATCH 128
#define CH 8             // channels per patch = L / N_PATCHES
#define D 64
#define WIN 9            // key patches ahead (diff in 1..9)
#define MAXK (WIN*CH)    // 72
#define KSTR 73          // row stride in 16B units (odd -> bank rotation)

typedef _Float16 h2 __attribute__((ext_vector_type(2)));

static __device__ __forceinline__ h2 pkrtz(float x, float y) {
    return __builtin_bit_cast(h2, __builtin_amdgcn_cvt_pkrtz(x, y));
}
static __device__ __forceinline__ unsigned h2u(h2 h) { return __builtin_bit_cast(unsigned, h); }
static __device__ __forceinline__ h2 u2h(unsigned u) { return __builtin_bit_cast(h2, u); }

__global__ __launch_bounds__(256) void signed_attn_kernel(
    const float* __restrict__ Q, const float* __restrict__ K,
    const float* __restrict__ V, const float* __restrict__ logscale,
    float* __restrict__ O)
{
    // chunk-major packed-f16: dword (c*KSTR+k)*4 + j holds d = 8c+2j, 8c+2j+1 of key k
    __shared__ unsigned sK[8 * KSTR * 4];      // 9344 B
    __shared__ unsigned sV[8 * KSTR * 4];      // 9344 B
    __shared__ unsigned sA[CH * MAXK];         // 2304 B, dup-packed (a,a) f16
    // total 20992 B -> LDS allows 7 blocks/CU

    const int tid = threadIdx.x;
    const int bid = blockIdx.x;
    const int p   = bid & (NPATCH - 1);
    const int bh  = bid >> 7;

    const long long base  = (long long)bh * (NPATCH * CH) * D;
    const long long qbase = base + (long long)(p * CH) * D;
    float4*       Og4 = (float4*)(O + qbase);
    const float4* Qg4 = (const float4*)(Q + qbase);

    const int npk = min(WIN, NPATCH - 1 - p);
    const int nk  = npk * CH;                  // multiple of 8, or 0

    if (nk == 0) {                             // patch 127: fully masked -> A==0 exactly
        if (tid < CH * D / 4) Og4[tid] = make_float4(0.f, 0.f, 0.f, 0.f);
        return;
    }

    const float scale = fminf(fmaxf(__expf(logscale[0]), 1.0f), 30.0f) * 0.125f;

    // ---- stage K,V: global f32 float4 -> packed f16 pairs in LDS (ds_write_b64) ----
    {
        const long long kbase = base + (long long)((p + 1) * CH) * D;
        const float4* Kg = (const float4*)(K + kbase);
        const float4* Vg = (const float4*)(V + kbase);
        const int n4 = nk * 16;
        for (int i = tid; i < n4; i += 256) {
            const int k = i >> 4, d4 = i & 15, c = d4 >> 1, hh = d4 & 1;
            const float4 kv = Kg[i];
            const float4 vv = Vg[i];
            const int dst = (c * KSTR + k) * 4 + hh * 2;
            *(uint2*)&sK[dst] = make_uint2(h2u(pkrtz(kv.x, kv.y)), h2u(pkrtz(kv.z, kv.w)));
            *(uint2*)&sV[dst] = make_uint2(h2u(pkrtz(vv.x, vv.y)), h2u(pkrtz(vv.z, vv.w)));
        }
        // zero V tail rows so A(=0) * garbage can't produce NaN in the AV loop
        for (int i = tid; i < (MAXK - nk) * 8; i += 256) {
            const int k = nk + (i >> 3), c = i & 7;
            *(uint4*)&sV[(c * KSTR + k) * 4] = make_uint4(0u, 0u, 0u, 0u);
        }
    }
    __syncthreads();

    // ---- scores: half-wave owns q = tid>>5; lane owns keys {lane, lane+32, lane+64(<8)} ----
    const int q    = tid >> 5;
    const int lane = tid & 31;
    const int k2   = (lane < MAXK - 64) ? (64 + lane) : lane;   // alias for lane>=8 (masked)

    h2 a0 = 0, a1 = 0, a2 = 0;
    const float4* Qrow = Qg4 + q * 16;
#pragma unroll 4
    for (int c = 0; c < 8; ++c) {
        const float4 qv0 = Qrow[2 * c];         // d = 8c..8c+3 (L1-resident)
        const float4 qv1 = Qrow[2 * c + 1];     // d = 8c+4..8c+7
        const h2 qh0 = pkrtz(qv0.x, qv0.y);
        const h2 qh1 = pkrtz(qv0.z, qv0.w);
        const h2 qh2 = pkrtz(qv1.x, qv1.y);
        const h2 qh3 = pkrtz(qv1.z, qv1.w);
        const uint4 k0 = *(const uint4*)&sK[(c * KSTR + lane) * 4];
        const uint4 k1 = *(const uint4*)&sK[(c * KSTR + lane + 32) * 4];
        const uint4 kx = *(const uint4*)&sK[(c * KSTR + k2) * 4];
        a0 += qh0 * u2h(k0.x) + qh1 * u2h(k0.y) + qh2 * u2h(k0.z) + qh3 * u2h(k0.w);
        a1 += qh0 * u2h(k1.x) + qh1 * u2h(k1.y) + qh2 * u2h(k1.z) + qh3 * u2h(k1.w);
        a2 += qh0 * u2h(kx.x) + qh1 * u2h(kx.y) + qh2 * u2h(kx.z) + qh3 * u2h(kx.w);
    }
    const float c0 = (float)a0[0] + (float)a0[1];
    const float c1 = (float)a1[0] + (float)a1[1];
    const float c2 = (float)a2[0] + (float)a2[1];

    // ---- dual softmax, registers + width-32 shuffle butterflies ----
    const bool v0 = (lane      < nk);
    const bool v1 = (lane + 32 < nk);
    const bool v2 = (lane < 8) && (lane + 64 < nk);
    const float t0 = scale * c0, t1 = scale * c1, t2 = scale * c2;

    float mp = fmaxf(fmaxf(v0 ?  t0 : -1e30f, v1 ?  t1 : -1e30f), v2 ?  t2 : -1e30f);
    float mn = fmaxf(fmaxf(v0 ? -t0 : -1e30f, v1 ? -t1 : -1e30f), v2 ? -t2 : -1e30f);
#pragma unroll
    for (int off = 16; off > 0; off >>= 1) {
        mp = fmaxf(mp, __shfl_xor(mp, off, 32));
        mn = fmaxf(mn, __shfl_xor(mn, off, 32));
    }

    const float ep0 = v0 ? __expf( t0 - mp) : 0.f;
    const float en0 = v0 ? __expf(-t0 - mn) : 0.f;
    const float ep1 = v1 ? __expf( t1 - mp) : 0.f;
    const float en1 = v1 ? __expf(-t1 - mn) : 0.f;
    const float ep2 = v2 ? __expf( t2 - mp) : 0.f;
    const float en2 = v2 ? __expf(-t2 - mn) : 0.f;

    float sp = ep0 + ep1 + ep2;
    float sn = en0 + en1 + en2;
#pragma unroll
    for (int off = 16; off > 0; off >>= 1) {
        sp += __shfl_xor(sp, off, 32);
        sn += __shfl_xor(sn, off, 32);
    }
    const float rp = 1.f / sp, rn = 1.f / sn;

    const float A0 = ep0 * rp - en0 * rn;      // invalid keys -> exact 0
    const float A1 = ep1 * rp - en1 * rn;
    const float A2 = ep2 * rp - en2 * rn;
    sA[q * MAXK + lane]      = h2u(pkrtz(A0, A0));
    sA[q * MAXK + lane + 32] = h2u(pkrtz(A1, A1));
    if (lane < 8) sA[q * MAXK + lane + 64] = h2u(pkrtz(A2, A2));
    __syncthreads();

    // ---- O = A * V : thread = (q, kQ quarter, d-chunk c); packed-f16 accumulate ----
    const int c  = tid & 7;
    const int kQ = (tid >> 3) & 3;
    const int qa = tid >> 5;
    const int kst = kQ * 18;

    h2 acc0 = 0, acc1 = 0, acc2 = 0, acc3 = 0;
#pragma unroll 3
    for (int j = 0; j < 18; ++j) {
        const int k = kst + j;                            // A==0 & V==0 past nk
        const h2 av = u2h(sA[qa * MAXK + k]);             // broadcast (a,a)
        const uint4 vv = *(const uint4*)&sV[(c * KSTR + k) * 4];
        acc0 += u2h(vv.x) * av;
        acc1 += u2h(vv.y) * av;
        acc2 += u2h(vv.z) * av;
        acc3 += u2h(vv.w) * av;
    }
    // reduce over kQ (lane bits 3,4)
#pragma unroll
    for (int off = 8; off <= 16; off <<= 1) {
        acc0 += __builtin_bit_cast(h2, __shfl_xor(__builtin_bit_cast(float, acc0), off));
        acc1 += __builtin_bit_cast(h2, __shfl_xor(__builtin_bit_cast(float, acc1), off));
        acc2 += __builtin_bit_cast(h2, __shfl_xor(__builtin_bit_cast(float, acc2), off));
        acc3 += __builtin_bit_cast(h2, __shfl_xor(__builtin_bit_cast(float, acc3), off));
    }
    if (kQ == 0) {
        const float4 o0 = make_float4((float)acc0[0], (float)acc0[1],
                                      (float)acc1[0], (float)acc1[1]);
        const float4 o1 = make_float4((float)acc2[0], (float)acc2[1],
                                      (float)acc3[0], (float)acc3[1]);
        Og4[qa * 16 + 2 * c]     = o0;   // d = 8c..8c+3
        Og4[qa * 16 + 2 * c + 1] = o1;   // d = 8c+4..8c+7
    }
}

extern "C" void kernel_launch(void* const* d_in, const int* in_sizes, int n_in,
                              void* d_out, int out_size, void* d_ws, size_t ws_size,
                              hipStream_t stream) {
    const float* Q  = (const float*)d_in[0];
    const float* K  = (const float*)d_in[1];
    const float* V  = (const float*)d_in[2];
    const float* ls = (const float*)d_in[3];
    float* O = (float*)d_out;

    const int L = 1024;
    const int nBH = in_sizes[0] / (L * D);     // B*H = 32
    dim3 grid(nBH * NPATCH);                   // 4096 blocks
    signed_attn_kernel<<<grid, 256, 0, stream>>>(Q, K, V, ls, O);
}

// Round 6
// 88.149 us; speedup vs baseline: 1.1813x; 1.1813x over previous
//
#include <hip/hip_runtime.h>
#include <math.h>

#define NPATCH 128
#define CH 8             // channels per patch = L / N_PATCHES
#define D 64
#define WIN 9            // key patches ahead (diff in 1..9)
#define G 4              // query patches per block
#define NKEY 96          // staged keys = (G+WIN-1)*CH
#define STR 97           // key-slot stride per d-chunk, 16B units (odd)

typedef _Float16 h2 __attribute__((ext_vector_type(2)));

static __device__ __forceinline__ h2 pkrtz(float x, float y) {
    return __builtin_bit_cast(h2, __builtin_amdgcn_cvt_pkrtz(x, y));
}
static __device__ __forceinline__ unsigned h2u(h2 h) { return __builtin_bit_cast(unsigned, h); }
static __device__ __forceinline__ h2 u2h(unsigned u) { return __builtin_bit_cast(h2, u); }

__global__ __launch_bounds__(256) void signed_attn_kernel(
    const float* __restrict__ Q, const float* __restrict__ K,
    const float* __restrict__ V, const float* __restrict__ logscale,
    float* __restrict__ O)
{
    // chunk-major packed-f16: dword (c*STR+k)*4 + j holds dims 8c+2j,8c+2j+1 of key k
    __shared__ unsigned sK[8 * STR * 4];      // 12416 B
    __shared__ unsigned sV[8 * STR * 4];      // 12416 B
    __shared__ unsigned sA[G * CH * 72];      //  9216 B, dup-packed (a,a) f16
    // total 34048 B -> 4 blocks/CU

    const int tid = threadIdx.x;
    const int grp = blockIdx.x & 31;          // 32 patch-groups
    const int bh  = blockIdx.x >> 5;          // B*H
    const int p0  = grp * G;

    const long long base = (long long)bh * (NPATCH * CH) * D;
    const int nst = min(NKEY, (NPATCH - 1 - p0) * CH);   // staged keys (>=24)

    const float scale = fminf(fmaxf(__expf(logscale[0]), 1.0f), 30.0f) * 0.125f;

    // ---- stage K,V: patches p0+1 .. p0+12 (clipped), f32 -> packed f16 ----
    {
        const long long kb = base + (long long)((p0 + 1) * CH) * D;
        const float4* Kg = (const float4*)(K + kb);
        const float4* Vg = (const float4*)(V + kb);
        for (int i = tid; i < nst * 16; i += 256) {
            const int k = i >> 4, d4 = i & 15, c = d4 >> 1, hh = d4 & 1;
            const float4 kv = Kg[i];
            const float4 vv = Vg[i];
            const int dst = (c * STR + k) * 4 + hh * 2;
            *(uint2*)&sK[dst] = make_uint2(h2u(pkrtz(kv.x, kv.y)), h2u(pkrtz(kv.z, kv.w)));
            *(uint2*)&sV[dst] = make_uint2(h2u(pkrtz(vv.x, vv.y)), h2u(pkrtz(vv.z, vv.w)));
        }
        // zero V tail so A(=0) * garbage can't make NaN; K tail is predicate-masked
        for (int i = tid; i < (NKEY - nst) * 8; i += 256) {
            const int k = nst + (i >> 3), c = i & 7;
            *(uint4*)&sV[(c * STR + k) * 4] = make_uint4(0u, 0u, 0u, 0u);
        }
    }
    __syncthreads();

    // ---- scores: thread = (q 0..31, lane8 0..7); lane owns keys lane8+8j, j=0..8 ----
    const int q     = tid >> 3;
    const int lane8 = tid & 7;
    const int g     = q >> 3;
    const int p     = p0 + g;
    const int krel0 = g * CH;                               // window offset in staged keys
    const int kvmax = min(72, (NPATCH - 1 - p) * CH);       // valid keys for this query patch

    const float4* Qrow = (const float4*)(Q + base + (long long)(p * CH + (q & 7)) * D);

    h2 acc[9];
#pragma unroll
    for (int j = 0; j < 9; ++j) acc[j] = 0;

#pragma unroll 2
    for (int c = 0; c < 8; ++c) {
        const float4 q0 = Qrow[2 * c];
        const float4 q1 = Qrow[2 * c + 1];
        const h2 qh0 = pkrtz(q0.x, q0.y), qh1 = pkrtz(q0.z, q0.w);
        const h2 qh2 = pkrtz(q1.x, q1.y), qh3 = pkrtz(q1.z, q1.w);
        const unsigned* kc = &sK[c * STR * 4];
#pragma unroll
        for (int j = 0; j < 9; ++j) {
            const uint4 kv = *(const uint4*)&kc[(krel0 + lane8 + 8 * j) * 4];
            acc[j] += qh0 * u2h(kv.x) + qh1 * u2h(kv.y) + qh2 * u2h(kv.z) + qh3 * u2h(kv.w);
        }
    }

    float t[9];
    bool  vld[9];
#pragma unroll
    for (int j = 0; j < 9; ++j) {
        t[j]   = scale * ((float)acc[j][0] + (float)acc[j][1]);
        vld[j] = (lane8 + 8 * j) < kvmax;
    }

    float mp = -1e30f, mn = -1e30f;
#pragma unroll
    for (int j = 0; j < 9; ++j) {
        mp = fmaxf(mp, vld[j] ?  t[j] : -1e30f);
        mn = fmaxf(mn, vld[j] ? -t[j] : -1e30f);
    }
#pragma unroll
    for (int off = 4; off > 0; off >>= 1) {                 // reduce over lane8 (bits 0..2)
        mp = fmaxf(mp, __shfl_xor(mp, off));
        mn = fmaxf(mn, __shfl_xor(mn, off));
    }

    float ep[9], en[9], sp = 0.f, sn = 0.f;
#pragma unroll
    for (int j = 0; j < 9; ++j) {
        ep[j] = vld[j] ? __expf( t[j] - mp) : 0.f;
        en[j] = vld[j] ? __expf(-t[j] - mn) : 0.f;
        sp += ep[j]; sn += en[j];
    }
#pragma unroll
    for (int off = 4; off > 0; off >>= 1) {
        sp += __shfl_xor(sp, off);
        sn += __shfl_xor(sn, off);
    }
    const float rp = (sp > 0.f) ? 1.f / sp : 0.f;           // all-masked row -> A = 0
    const float rn = (sn > 0.f) ? 1.f / sn : 0.f;

#pragma unroll
    for (int j = 0; j < 9; ++j) {
        const float A = ep[j] * rp - en[j] * rn;            // invalid -> exact 0
        sA[q * 72 + lane8 + 8 * j] = h2u(pkrtz(A, A));
    }
    __syncthreads();

    // ---- O = A * V : thread = (q 0..31, c 0..7) computes dims 8c..8c+7 of its query ----
    const int c = tid & 7;
    h2 o0 = 0, o1 = 0, o2 = 0, o3 = 0;
    const unsigned* vc   = &sV[c * STR * 4];
    const unsigned* arow = &sA[q * 72];
#pragma unroll 8
    for (int kk = 0; kk < 72; ++kk) {
        const h2 av = u2h(arow[kk]);                        // broadcast (a,a)
        const uint4 vv = *(const uint4*)&vc[(krel0 + kk) * 4];
        o0 += u2h(vv.x) * av;
        o1 += u2h(vv.y) * av;
        o2 += u2h(vv.z) * av;
        o3 += u2h(vv.w) * av;
    }
    float4* Og4 = (float4*)(O + base + (long long)(p * CH + (q & 7)) * D + c * 8);
    Og4[0] = make_float4((float)o0[0], (float)o0[1], (float)o1[0], (float)o1[1]);
    Og4[1] = make_float4((float)o2[0], (float)o2[1], (float)o3[0], (float)o3[1]);
}

extern "C" void kernel_launch(void* const* d_in, const int* in_sizes, int n_in,
                              void* d_out, int out_size, void* d_ws, size_t ws_size,
                              hipStream_t stream) {
    const float* Q  = (const float*)d_in[0];
    const float* K  = (const float*)d_in[1];
    const float* V  = (const float*)d_in[2];
    const float* ls = (const float*)d_in[3];
    float* O = (float*)d_out;

    const int L = 1024;
    const int nBH = in_sizes[0] / (L * D);     // B*H = 32
    dim3 grid(nBH * (NPATCH / G));             // 1024 blocks
    signed_attn_kernel<<<grid, 256, 0, stream>>>(Q, K, V, ls, O);
}

// Round 7
// 83.476 us; speedup vs baseline: 1.2474x; 1.0560x over previous
//
#include <hip/hip_runtime.h>
#include <math.h>

#define NPATCH 128
#define CH 8              // channels per patch = L / N_PATCHES
#define D 64
#define G 8               // query patches per block
#define NQ (G*CH)         // 64 queries/block
#define NKEY 128          // staged key slots
#define QSTR 72           // f16 row strides (all = 4 mod 8 dwords -> 2-way max)
#define KSTR 72
#define VSTR 136
#define PSTR 136

typedef __fp16 half8 __attribute__((ext_vector_type(8)));
typedef float  f32x4 __attribute__((ext_vector_type(4)));
typedef unsigned u32x4 __attribute__((ext_vector_type(4)));

static __device__ __forceinline__ unsigned pk(float x, float y) {
    return __builtin_bit_cast(unsigned, __builtin_amdgcn_cvt_pkrtz(x, y));
}
static __device__ __forceinline__ half8 ld8(const unsigned short* p) {
    return __builtin_bit_cast(half8, *(const u32x4*)p);
}

__global__ __launch_bounds__(256) void signed_attn_kernel(
    const float* __restrict__ Q, const float* __restrict__ K,
    const float* __restrict__ V, const float* __restrict__ logscale,
    float* __restrict__ O)
{
    __shared__ __align__(16) unsigned short sQ[NQ * QSTR];     //  9216 B
    __shared__ __align__(16) unsigned short sK[NKEY * KSTR];   // 18432 B
    __shared__ __align__(16) unsigned short sVt[D * VSTR];     // 17408 B  (V transposed)
    __shared__ __align__(16) unsigned short sP[NQ * PSTR];     // 17408 B
    // total 62464 B -> 2 blocks/CU; 512 blocks = exactly 2/CU

    const int tid = threadIdx.x;
    const int grp = blockIdx.x & 15;          // 16 patch-groups
    const int bh  = blockIdx.x >> 4;
    const int p0  = grp * G;

    const long long base = (long long)bh * (NPATCH * CH) * D;
    const int nst = min(NKEY, (NPATCH - 1 - p0) * CH);   // valid staged keys

    const float scale = fminf(fmaxf(__expf(logscale[0]), 1.0f), 30.0f) * 0.125f;

    // ---- stage Q [q][d] f16 ----
    const float4* Qg = (const float4*)(Q + base + (long long)(p0 * CH) * D);
    for (int i = tid; i < NQ * 16; i += 256) {
        const int row = i >> 4, d4 = i & 15;
        const float4 v = Qg[i];
        *(uint2*)&sQ[row * QSTR + d4 * 4] = make_uint2(pk(v.x, v.y), pk(v.z, v.w));
    }
    // ---- stage K [key][d] f16, zero tail ----
    const float4* Kg = (const float4*)(K + base + (long long)((p0 + 1) * CH) * D);
    for (int i = tid; i < NKEY * 16; i += 256) {
        const int row = i >> 4, d4 = i & 15;
        uint2 w = make_uint2(0u, 0u);
        if (row < nst) { const float4 v = Kg[i]; w = make_uint2(pk(v.x, v.y), pk(v.z, v.w)); }
        *(uint2*)&sK[row * KSTR + d4 * 4] = w;
    }
    // ---- stage V transposed: Vt[d][key] f16, key-pairs packed per dword, zero tail ----
    const float4* Vg = (const float4*)(V + base + (long long)((p0 + 1) * CH) * D);
    for (int u = tid; u < 64 * 16; u += 256) {            // (keypair, dim-quad)
        const int kp = u & 63, dq = u >> 6;
        float4 va = make_float4(0.f, 0.f, 0.f, 0.f);
        float4 vb = va;
        if (2 * kp < nst) { va = Vg[(2 * kp) * 16 + dq]; vb = Vg[(2 * kp + 1) * 16 + dq]; }
        *(unsigned*)&sVt[(dq * 4 + 0) * VSTR + 2 * kp] = pk(va.x, vb.x);
        *(unsigned*)&sVt[(dq * 4 + 1) * VSTR + 2 * kp] = pk(va.y, vb.y);
        *(unsigned*)&sVt[(dq * 4 + 2) * VSTR + 2 * kp] = pk(va.z, vb.z);
        *(unsigned*)&sVt[(dq * 4 + 3) * VSTR + 2 * kp] = pk(va.w, vb.w);
    }
    __syncthreads();   // the only barrier

    const int wav = tid >> 6, lane = tid & 63;
    const int col = lane & 15, quad = lane >> 4;

    // ---- QK^T: wave owns m-tile wav (queries wav*16..+15), 8 n-tiles, K=64 ----
    const half8 a0 = ld8(&sQ[(wav * 16 + col) * QSTR + quad * 8]);
    const half8 a1 = ld8(&sQ[(wav * 16 + col) * QSTR + 32 + quad * 8]);

    f32x4 acc[8];
#pragma unroll
    for (int t = 0; t < 8; ++t) acc[t] = (f32x4){0.f, 0.f, 0.f, 0.f};
#pragma unroll
    for (int t = 0; t < 8; ++t) {
        const half8 b0 = ld8(&sK[(t * 16 + col) * KSTR + quad * 8]);
        const half8 b1 = ld8(&sK[(t * 16 + col) * KSTR + 32 + quad * 8]);
        acc[t] = __builtin_amdgcn_mfma_f32_16x16x32_f16(a0, b0, acc[t], 0, 0, 0);
        acc[t] = __builtin_amdgcn_mfma_f32_16x16x32_f16(a1, b1, acc[t], 0, 0, 0);
    }

    // ---- dual softmax: lane holds rows quad*4+r, cols col+16t; butterfly over lane bits 0..3 ----
#pragma unroll
    for (int r = 0; r < 4; ++r) {
        const int q   = wav * 16 + quad * 4 + r;          // block-local query
        const int kr0 = (q >> 3) * 8;                     // window start in staged keys
        const int kmx = min(kr0 + 72, nst);

        float tv[8]; bool vl[8];
        float mp = -1e30f, mn = -1e30f;
#pragma unroll
        for (int t = 0; t < 8; ++t) {
            const int c = col + 16 * t;
            tv[t] = scale * acc[t][r];
            vl[t] = (c >= kr0) && (c < kmx);
            mp = fmaxf(mp, vl[t] ?  tv[t] : -1e30f);
            mn = fmaxf(mn, vl[t] ? -tv[t] : -1e30f);
        }
#pragma unroll
        for (int off = 1; off < 16; off <<= 1) {
            mp = fmaxf(mp, __shfl_xor(mp, off));
            mn = fmaxf(mn, __shfl_xor(mn, off));
        }
        float ep[8], en[8], sp = 0.f, sn = 0.f;
#pragma unroll
        for (int t = 0; t < 8; ++t) {
            ep[t] = vl[t] ? __expf( tv[t] - mp) : 0.f;
            en[t] = vl[t] ? __expf(-tv[t] - mn) : 0.f;
            sp += ep[t]; sn += en[t];
        }
#pragma unroll
        for (int off = 1; off < 16; off <<= 1) {
            sp += __shfl_xor(sp, off);
            sn += __shfl_xor(sn, off);
        }
        const float rp = (sp > 0.f) ? 1.f / sp : 0.f;     // fully-masked row -> P = 0
        const float rn = (sn > 0.f) ? 1.f / sn : 0.f;
#pragma unroll
        for (int t = 0; t < 8; ++t) {
            const float A = ep[t] * rp - en[t] * rn;      // invalid -> exact 0
            sP[q * PSTR + col + 16 * t] = (unsigned short)pk(A, A);
        }
    }
    // wave reads back only its own 16 P rows -> no barrier (lgkmcnt ordering suffices)

    // ---- PV: O[16 x 64] = P[16 x 128] * Vt^T, 4 n-tiles, K=128 ----
    f32x4 oc[4];
#pragma unroll
    for (int t = 0; t < 4; ++t) oc[t] = (f32x4){0.f, 0.f, 0.f, 0.f};
#pragma unroll
    for (int kq = 0; kq < 4; ++kq) {
        const half8 ap = ld8(&sP[(wav * 16 + col) * PSTR + kq * 32 + quad * 8]);
#pragma unroll
        for (int t = 0; t < 4; ++t) {
            const half8 bv = ld8(&sVt[(t * 16 + col) * VSTR + kq * 32 + quad * 8]);
            oc[t] = __builtin_amdgcn_mfma_f32_16x16x32_f16(ap, bv, oc[t], 0, 0, 0);
        }
    }

    // ---- store O: lane holds rows quad*4+r, cols col+16t ----
    float* Ob = O + base + (long long)(p0 * CH) * D;
#pragma unroll
    for (int t = 0; t < 4; ++t) {
#pragma unroll
        for (int r = 0; r < 4; ++r) {
            Ob[(wav * 16 + quad * 4 + r) * D + t * 16 + col] = oc[t][r];
        }
    }
}

extern "C" void kernel_launch(void* const* d_in, const int* in_sizes, int n_in,
                              void* d_out, int out_size, void* d_ws, size_t ws_size,
                              hipStream_t stream) {
    const float* Q  = (const float*)d_in[0];
    const float* K  = (const float*)d_in[1];
    const float* V  = (const float*)d_in[2];
    const float* ls = (const float*)d_in[3];
    float* O = (float*)d_out;

    const int L = 1024;
    const int nBH = in_sizes[0] / (L * D);    // B*H = 32
    dim3 grid(nBH * (NPATCH / G));            // 512 blocks
    signed_attn_kernel<<<grid, 256, 0, stream>>>(Q, K, V, ls, O);
}

// Round 9
// 82.499 us; speedup vs baseline: 1.2621x; 1.0118x over previous
//
#include <hip/hip_runtime.h>
#include <math.h>

#define NPATCH 128
#define CH 8              // channels per patch = L / N_PATCHES
#define D 64
#define G 8               // query patches per block
#define NQ (G*CH)         // 64 queries/block
#define NKEY 128          // staged key slots
#define KSTR 72           // f16 strides: 72,136 ≡ 4 (mod 8) dwords; 100 -> 2-way max
#define VSTR 136
#define PSTR 100          // per-wave-relative P row: 96 keys + pad

typedef __fp16 half8 __attribute__((ext_vector_type(8)));
typedef float  f32x4 __attribute__((ext_vector_type(4)));
typedef unsigned u32x4 __attribute__((ext_vector_type(4)));

static __device__ __forceinline__ unsigned pk(float x, float y) {
    return __builtin_bit_cast(unsigned, __builtin_amdgcn_cvt_pkrtz(x, y));
}
static __device__ __forceinline__ half8 ld8(const unsigned short* p) {
    return __builtin_bit_cast(half8, *(const u32x4*)p);
}
static __device__ __forceinline__ half8 mk8(const float4& a, const float4& b) {
    u32x4 u = { pk(a.x, a.y), pk(a.z, a.w), pk(b.x, b.y), pk(b.z, b.w) };
    return __builtin_bit_cast(half8, u);
}

__global__ __launch_bounds__(256) void signed_attn_kernel(
    const float* __restrict__ Q, const float* __restrict__ K,
    const float* __restrict__ V, const float* __restrict__ logscale,
    float* __restrict__ O)
{
    __shared__ __align__(16) unsigned short sK[NKEY * KSTR];   // 18432 B
    __shared__ __align__(16) unsigned short sVt[D * VSTR];     // 17408 B (V transposed)
    __shared__ __align__(16) unsigned short sP[NQ * PSTR];     // 12800 B (wave-relative)
    // total 48640 B -> 3 blocks/CU

    const int tid = threadIdx.x;
    const int grp = blockIdx.x & 15;          // 16 patch-groups
    const int bh  = blockIdx.x >> 4;
    const int p0  = grp * G;

    const long long base = (long long)bh * (NPATCH * CH) * D;
    const int nst = min(NKEY, (NPATCH - 1 - p0) * CH);   // valid staged keys

    const float scale = fminf(fmaxf(__expf(logscale[0]), 1.0f), 30.0f) * 0.125f;

    // ---- stage K [key][d] f16 (zero tail) and V transposed Vt[d][key] (zero tail) ----
    {
        const float4* Kg = (const float4*)(K + base + (long long)((p0 + 1) * CH) * D);
        for (int i = tid; i < NKEY * 16; i += 256) {
            const int row = i >> 4, d4 = i & 15;
            uint2 w = make_uint2(0u, 0u);
            if (row < nst) { const float4 v = Kg[i]; w = make_uint2(pk(v.x, v.y), pk(v.z, v.w)); }
            *(uint2*)&sK[row * KSTR + d4 * 4] = w;
        }
        const float4* Vg = (const float4*)(V + base + (long long)((p0 + 1) * CH) * D);
        for (int u = tid; u < 64 * 16; u += 256) {        // (keypair, dim-quad)
            const int kp = u & 63, dq = u >> 6;
            float4 va = make_float4(0.f, 0.f, 0.f, 0.f);
            float4 vb = va;
            if (2 * kp < nst) { va = Vg[(2 * kp) * 16 + dq]; vb = Vg[(2 * kp + 1) * 16 + dq]; }
            *(unsigned*)&sVt[(dq * 4 + 0) * VSTR + 2 * kp] = pk(va.x, vb.x);
            *(unsigned*)&sVt[(dq * 4 + 1) * VSTR + 2 * kp] = pk(va.y, vb.y);
            *(unsigned*)&sVt[(dq * 4 + 2) * VSTR + 2 * kp] = pk(va.z, vb.z);
            *(unsigned*)&sVt[(dq * 4 + 3) * VSTR + 2 * kp] = pk(va.w, vb.w);
        }
    }

    const int wav = tid >> 6, lane = tid & 63;
    const int col = lane & 15, quad = lane >> 4;

    // ---- Q A-frags straight from global (L1-resident; no LDS round-trip) ----
    const float4* Qg4 = (const float4*)(Q + base + (long long)(p0 * CH + wav * 16 + col) * D);
    const half8 a0 = mk8(Qg4[quad * 2],     Qg4[quad * 2 + 1]);     // d = 8q..8q+7
    const half8 a1 = mk8(Qg4[8 + quad * 2], Qg4[9 + quad * 2]);     // d = 32+8q..+7

    __syncthreads();   // the only barrier

    // ---- QK^T: wave w needs keys [16w, 16w+80) -> 5 n-tiles ----
    f32x4 acc[5];
#pragma unroll
    for (int t = 0; t < 5; ++t) acc[t] = (f32x4){0.f, 0.f, 0.f, 0.f};
#pragma unroll
    for (int t = 0; t < 5; ++t) {
        const int krow = (wav + t) * 16 + col;
        const half8 b0 = ld8(&sK[krow * KSTR + quad * 8]);
        const half8 b1 = ld8(&sK[krow * KSTR + 32 + quad * 8]);
        acc[t] = __builtin_amdgcn_mfma_f32_16x16x32_f16(a0, b0, acc[t], 0, 0, 0);
        acc[t] = __builtin_amdgcn_mfma_f32_16x16x32_f16(a1, b1, acc[t], 0, 0, 0);
    }

    // ---- dual softmax: lane holds rows quad*4+r, abs cols 16(w+t)+col ----
#pragma unroll
    for (int r = 0; r < 4; ++r) {
        const int q   = wav * 16 + quad * 4 + r;          // block-local query
        const int kr0 = (q >> 3) * 8;                     // window start (16w or 16w+8)
        const int kmx = min(kr0 + 72, nst);

        float tv[5]; bool vl[5];
        float mp = -1e30f, mn = -1e30f;
#pragma unroll
        for (int t = 0; t < 5; ++t) {
            const int c = (wav + t) * 16 + col;
            tv[t] = scale * acc[t][r];
            vl[t] = (c >= kr0) && (c < kmx);
            mp = fmaxf(mp, vl[t] ?  tv[t] : -1e30f);
            mn = fmaxf(mn, vl[t] ? -tv[t] : -1e30f);
        }
#pragma unroll
        for (int off = 1; off < 16; off <<= 1) {
            mp = fmaxf(mp, __shfl_xor(mp, off));
            mn = fmaxf(mn, __shfl_xor(mn, off));
        }
        float ep[5], en[5], sp = 0.f, sn = 0.f;
#pragma unroll
        for (int t = 0; t < 5; ++t) {
            ep[t] = vl[t] ? __expf( tv[t] - mp) : 0.f;
            en[t] = vl[t] ? __expf(-tv[t] - mn) : 0.f;
            sp += ep[t]; sn += en[t];
        }
#pragma unroll
        for (int off = 1; off < 16; off <<= 1) {
            sp += __shfl_xor(sp, off);
            sn += __shfl_xor(sn, off);
        }
        const float rp = (sp > 0.f) ? 1.f / sp : 0.f;     // fully-masked row -> P = 0
        const float rn = (sn > 0.f) ? 1.f / sn : 0.f;
#pragma unroll
        for (int t = 0; t < 5; ++t) {                     // rel col = 16t+col
            const float A = ep[t] * rp - en[t] * rn;      // invalid -> exact 0
            sP[q * PSTR + t * 16 + col] = (unsigned short)pk(A, A);
        }
        sP[q * PSTR + 80 + col] = 0;                      // zero-pad rel cols 80..95
    }
    // wave reads back only its own 16 P rows -> no barrier needed

    // ---- PV: O[16 x 64] = P[16 x 96] * Vt^T (abs key = 16w + rel) ----
    f32x4 oc[4];
#pragma unroll
    for (int t = 0; t < 4; ++t) oc[t] = (f32x4){0.f, 0.f, 0.f, 0.f};
#pragma unroll
    for (int kq = 0; kq < 3; ++kq) {
        const half8 ap = ld8(&sP[(wav * 16 + col) * PSTR + kq * 32 + quad * 8]);
        // abs key base; clamp to <=120 so reads stay in the WRITTEN region of sVt.
        // Clamped lanes (wave 3, kq 2, quad>=2) have P==0, so any finite value is fine.
        const int kb = wav * 16 + kq * 32 + quad * 8;
        const int kcl = (kb <= 120) ? kb : 120;
#pragma unroll
        for (int t = 0; t < 4; ++t) {
            const half8 bv = ld8(&sVt[(t * 16 + col) * VSTR + kcl]);
            oc[t] = __builtin_amdgcn_mfma_f32_16x16x32_f16(ap, bv, oc[t], 0, 0, 0);
        }
    }

    // ---- store O: lane holds rows quad*4+r, cols col+16t ----
    float* Ob = O + base + (long long)(p0 * CH) * D;
#pragma unroll
    for (int t = 0; t < 4; ++t) {
#pragma unroll
        for (int r = 0; r < 4; ++r) {
            Ob[(wav * 16 + quad * 4 + r) * D + t * 16 + col] = oc[t][r];
        }
    }
}

extern "C" void kernel_launch(void* const* d_in, const int* in_sizes, int n_in,
                              void* d_out, int out_size, void* d_ws, size_t ws_size,
                              hipStream_t stream) {
    const float* Q  = (const float*)d_in[0];
    const float* K  = (const float*)d_in[1];
    const float* V  = (const float*)d_in[2];
    const float* ls = (const float*)d_in[3];
    float* O = (float*)d_out;

    const int L = 1024;
    const int nBH = in_sizes[0] / (L * D);    // B*H = 32
    dim3 grid(nBH * (NPATCH / G));            // 512 blocks
    signed_attn_kernel<<<grid, 256, 0, stream>>>(Q, K, V, ls, O);
}